// Round 2
// baseline (708.885 us; speedup 1.0000x reference)
//
#include <hip/hip_runtime.h>

#define N_OPE 2048
#define N_MAC 1024
#define DIM   64
#define KOUT  128
#define NB    32

typedef __attribute__((ext_vector_type(8))) short short8;
typedef __attribute__((ext_vector_type(4))) float floatx4;

static __device__ __forceinline__ unsigned short f2bf(float f) {
    unsigned int u = __builtin_bit_cast(unsigned int, f);
    u += 0x7fffu + ((u >> 16) & 1u);   // round-to-nearest-even
    return (unsigned short)(u >> 16);
}
static __device__ __forceinline__ float bf2f(unsigned short h) {
    unsigned int u = ((unsigned int)h) << 16;
    return __builtin_bit_cast(float, u);
}

// ---------------- kernel 1 (fat): blocks 0..511 = h_ope MFMA + pq;
//                  blocks 512..1023 = adj bit-pack (streaming, BW-bound, overlaps ope) ----
// pack layout: pk[b][o][w] : u64, bit p of word w = mask of machine 64w+p. 8 MiB total.
__global__ __launch_bounds__(256, 2) void k_prep(const float* __restrict__ feat,
        const float* __restrict__ w, const float* __restrict__ alpha,
        unsigned short* __restrict__ h_f, float2* __restrict__ pq,
        const int* __restrict__ adj, const int* __restrict__ bidx,
        unsigned long long* __restrict__ pk)
{
    int wid = threadIdx.x >> 6, lane = threadIdx.x & 63;

    if (blockIdx.x >= 512) {
        // ---------------- pack path: 512 blocks x 4 waves = 2048 waves, 32 rows each ----
        int wave = (blockIdx.x - 512) * 4 + wid;       // 0..2047
        int r0 = wave * 32;                             // global row (b,o) base; 32 | 2048
        int b = r0 >> 11;
        int o0 = r0 & (N_OPE - 1);
        const int* at = adj + (size_t)bidx[b] * ((size_t)N_OPE * N_MAC);
        unsigned long long* dst = pk + ((size_t)b * N_OPE + o0) * 16;
        int L4 = (lane & 15) * 4;
        #pragma unroll 2
        for (int i = 0; i < 32; ++i) {
            const int* rp = at + (size_t)(o0 + i) * N_MAC + lane * 16;
            int4 a0 = *(const int4*)(rp);
            int4 a1 = *(const int4*)(rp + 4);
            int4 a2 = *(const int4*)(rp + 8);
            int4 a3 = *(const int4*)(rp + 12);
            unsigned h = (a0.x & 1)        | ((a0.y & 1) << 1)  | ((a0.z & 1) << 2)  | ((a0.w & 1) << 3)
                       | ((a1.x & 1) << 4) | ((a1.y & 1) << 5)  | ((a1.z & 1) << 6)  | ((a1.w & 1) << 7)
                       | ((a2.x & 1) << 8) | ((a2.y & 1) << 9)  | ((a2.z & 1) << 10) | ((a2.w & 1) << 11)
                       | ((a3.x & 1) << 12)| ((a3.y & 1) << 13) | ((a3.z & 1) << 14) | ((a3.w & 1) << 15);
            unsigned h0 = (unsigned)__shfl((int)h, L4);
            unsigned h1 = (unsigned)__shfl((int)h, L4 + 1);
            unsigned h2 = (unsigned)__shfl((int)h, L4 + 2);
            unsigned h3 = (unsigned)__shfl((int)h, L4 + 3);
            unsigned long long W = (unsigned long long)(h0 & 0xffffu)
                                 | ((unsigned long long)(h1 & 0xffffu) << 16)
                                 | ((unsigned long long)(h2 & 0xffffu) << 32)
                                 | ((unsigned long long)(h3 & 0xffffu) << 48);
            if (lane < 16)
                dst[(size_t)i * 16 + lane] = W;
        }
        return;
    }

    // ---------------- ope path (unchanged): h_ope via 3-term bf16 MFMA + pq ----
    int L = lane & 15, q = lane >> 4;
    int base = blockIdx.x * 128 + wid * 32;           // row base for this wave
    int b = base >> 11;                                // rows per batch = 2048
    int o0w = base & (N_OPE - 1);

    float fA[2][2][8];                                 // [mf][ks][j]
    #pragma unroll
    for (int mf = 0; mf < 2; ++mf) {
        const float* fr = feat + (size_t)(base + mf * 16 + L) * DIM + q * 8;
        #pragma unroll
        for (int ks = 0; ks < 2; ++ks) {
            float4 v0 = *(const float4*)(fr + ks * 32);
            float4 v1 = *(const float4*)(fr + ks * 32 + 4);
            fA[mf][ks][0] = v0.x; fA[mf][ks][1] = v0.y; fA[mf][ks][2] = v0.z; fA[mf][ks][3] = v0.w;
            fA[mf][ks][4] = v1.x; fA[mf][ks][5] = v1.y; fA[mf][ks][6] = v1.z; fA[mf][ks][7] = v1.w;
        }
    }

    short8 Ah[2][2], Al[2][2];
    #pragma unroll
    for (int mf = 0; mf < 2; ++mf)
        #pragma unroll
        for (int ks = 0; ks < 2; ++ks)
            #pragma unroll
            for (int j = 0; j < 8; ++j) {
                float x = fA[mf][ks][j];
                unsigned short h = f2bf(x);
                Ah[mf][ks][j] = (short)h;
                Al[mf][ks][j] = (short)f2bf(x - bf2f(h));
            }

    floatx4 C[2][8];
    #pragma unroll
    for (int mf = 0; mf < 2; ++mf)
        #pragma unroll
        for (int nf = 0; nf < 8; ++nf) C[mf][nf] = (floatx4)0.f;

    #pragma unroll
    for (int ks = 0; ks < 2; ++ks) {
        #pragma unroll
        for (int nf = 0; nf < 8; ++nf) {
            const float* wp = w + (size_t)(nf * 16 + L) * DIM + ks * 32 + q * 8;
            float4 u0 = *(const float4*)(wp);
            float4 u1 = *(const float4*)(wp + 4);
            float bw[8] = {u0.x, u0.y, u0.z, u0.w, u1.x, u1.y, u1.z, u1.w};
            short8 Bh, Bl;
            #pragma unroll
            for (int j = 0; j < 8; ++j) {
                unsigned short h = f2bf(bw[j]);
                Bh[j] = (short)h;
                Bl[j] = (short)f2bf(bw[j] - bf2f(h));
            }
            #pragma unroll
            for (int mf = 0; mf < 2; ++mf) {
                C[mf][nf] = __builtin_amdgcn_mfma_f32_16x16x32_bf16(Ah[mf][ks], Bh, C[mf][nf], 0, 0, 0);
                C[mf][nf] = __builtin_amdgcn_mfma_f32_16x16x32_bf16(Al[mf][ks], Bh, C[mf][nf], 0, 0, 0);
                C[mf][nf] = __builtin_amdgcn_mfma_f32_16x16x32_bf16(Ah[mf][ks], Bl, C[mf][nf], 0, 0, 0);
            }
        }
    }

    // ---- pq from exact fp32 C . alpha (row = mf*16+q*4+r, col = nf*16+L)
    float alf[8];
    #pragma unroll
    for (int nf = 0; nf < 8; ++nf) alf[nf] = alpha[nf * 16 + L];
    #pragma unroll
    for (int mf = 0; mf < 2; ++mf) {
        #pragma unroll
        for (int r = 0; r < 4; ++r) {
            float s = 0.f;
            #pragma unroll
            for (int nf = 0; nf < 8; ++nf) s = fmaf(C[mf][nf][r], alf[nf], s);
            s += __shfl_xor(s, 1); s += __shfl_xor(s, 2);
            s += __shfl_xor(s, 4); s += __shfl_xor(s, 8);
            if (L == 0)
                pq[base + mf * 16 + q * 4 + r] = make_float2(__expf(s), __expf(0.2f * s));
        }
    }

    // ---- transpose via per-wave LDS slice (stride 40 shorts => 16B-aligned b128 reads)
    __shared__ unsigned short T[4][128 * 40];
    #pragma unroll
    for (int mf = 0; mf < 2; ++mf)
        #pragma unroll
        for (int nf = 0; nf < 8; ++nf)
            #pragma unroll
            for (int r = 0; r < 4; ++r)
                T[wid][(nf * 16 + L) * 40 + mf * 16 + q * 4 + r] = f2bf(C[mf][nf][r]);
    __syncthreads();

    // ---- fragment-major store: lane (L,q) emits exactly k_attn lane's short8
    int oc = o0w >> 5;
    unsigned short* dst = h_f + ((((size_t)b * 64 + oc) * 8) * 64 + lane) * 8;
    #pragma unroll
    for (int nf = 0; nf < 8; ++nf) {
        short8 v = *(const short8*)&T[wid][(nf * 16 + L) * 40 + q * 8];
        *(short8*)(dst + (size_t)nf * 512) = v;
    }
}

// ---------------- kernel 2: fully fused mask->softmax->MFMA + h_res ----------------
// 4 waves, 4-way K-split, even/odd m-pairing, fragment-major B loads.
// Masks now come from the packed bitmap (L2/L3-resident, broadcast loads) instead of
// the 256 MB int32 adj stream -> the main loop has no HBM-latency-bound gather left.
__global__ __launch_bounds__(256) void k_attn(
        const unsigned long long* __restrict__ pk,
        const unsigned short* __restrict__ h_f,
        const float2* __restrict__ pq,
        const float* __restrict__ feat_mac,
        const float* __restrict__ mac_w, const float* __restrict__ mac_alpha,
        const float* __restrict__ res_w,
        float* __restrict__ out)
{
    int b  = blockIdx.y;
    int m0 = blockIdx.x * 32;
    int t = threadIdx.x, wv = t >> 6, lane = t & 63;
    int L = lane & 15, q = lane >> 4;

    __shared__ float buf0[32 * 132];
    __shared__ float buf1[32 * 132];
    __shared__ float waS[64];
    __shared__ float amS[32];
    __shared__ float DS[4][32];

    // ---- wa[d] = sum_n mac_w[n][d]*mac_alpha[n]
    {
        int d = t & 63, seg = t >> 6;
        float p = 0.f;
        #pragma unroll 8
        for (int n = seg * 32; n < seg * 32 + 32; ++n)
            p = fmaf(mac_w[n * DIM + d], mac_alpha[n], p);
        buf0[seg * 64 + d] = p;
    }
    __syncthreads();
    if (t < 64) waS[t] = buf0[t] + buf0[64 + t] + buf0[128 + t] + buf0[192 + t];
    __syncthreads();
    // ---- am[m] = feat_mac[b][m0+m] . waS
    {
        int row = t & 31, seg = t >> 5;
        const float* fr = feat_mac + ((size_t)b * N_MAC + m0 + row) * DIM + seg * 8;
        float p = 0.f;
        #pragma unroll
        for (int k = 0; k < 8; ++k) p = fmaf(fr[k], waS[seg * 8 + k], p);
        buf1[seg * 32 + row] = p;
    }
    __syncthreads();
    if (t < 32) {
        float s = 0.f;
        #pragma unroll
        for (int sg = 0; sg < 8; ++sg) s += buf1[sg * 32 + t];
        amS[t] = s;
    }
    __syncthreads();

    float2 amv = *(const float2*)&amS[2 * L];          // frag0: m0+2L, frag1: m0+2L+1
    float pM0 = __expf(amv.x), qM0 = __expf(0.2f * amv.x);
    float pM1 = __expf(amv.y), qM1 = __expf(0.2f * amv.y);

    const unsigned long long* pkb = pk + (size_t)b * N_OPE * 16;
    const unsigned short* hfb = h_f + (size_t)b * (64 * 8 * 64 * 8);
    const float2* pqb = pq + (size_t)b * N_OPE;
    int wi = m0 >> 6;                      // u64 word index for this machine block
    int sft = (m0 & 63) + 2 * L;           // bit of even machine; +1 = odd

    floatx4 C0[8], C1[8];
    #pragma unroll
    for (int i = 0; i < 8; ++i) { C0[i] = (floatx4)0.f; C1[i] = (floatx4)0.f; }
    float den0 = 0.f, den1 = 0.f;

    int oBeg = wv * (N_OPE / 4);
    for (int o0 = oBeg; o0 < oBeg + N_OPE / 4; o0 += 32) {
        int ob = o0 + q * 8;
        float4 pv0 = *(const float4*)(pqb + ob);
        float4 pv1 = *(const float4*)(pqb + ob + 2);
        float4 pv2 = *(const float4*)(pqb + ob + 4);
        float4 pv3 = *(const float4*)(pqb + ob + 6);
        float pA[8] = {pv0.x, pv0.z, pv1.x, pv1.z, pv2.x, pv2.z, pv3.x, pv3.z};
        float qA[8] = {pv0.y, pv0.w, pv1.y, pv1.w, pv2.y, pv2.w, pv3.y, pv3.w};

        unsigned long long wm[8];
        #pragma unroll
        for (int j = 0; j < 8; ++j)
            wm[j] = pkb[(size_t)(ob + j) * 16 + wi];

        const unsigned short* fp = hfb + (((size_t)(o0 >> 5) * 8) * 64 + lane) * 8;
        short8 Bf[8];
        #pragma unroll
        for (int nf = 0; nf < 8; ++nf)
            Bf[nf] = *(const short8*)(fp + (size_t)nf * 512);

        float w0v[8], w1v[8];
        #pragma unroll
        for (int j = 0; j < 8; ++j) {
            float tp0 = pA[j] * pM0;
            float w0 = (tp0 >= 1.0f) ? tp0 : qA[j] * qM0;
            w0 = ((wm[j] >> sft) & 1ull) ? w0 : 0.f;
            den0 += w0; w0v[j] = w0;
            float tp1 = pA[j] * pM1;
            float w1 = (tp1 >= 1.0f) ? tp1 : qA[j] * qM1;
            w1 = ((wm[j] >> (sft + 1)) & 1ull) ? w1 : 0.f;
            den1 += w1; w1v[j] = w1;
        }
        int4 A0i, A1i;
        #pragma unroll
        for (int j2 = 0; j2 < 4; ++j2) {
            unsigned lo0 = __builtin_bit_cast(unsigned, w0v[2 * j2])     + 0x8000u;
            unsigned hi0 = __builtin_bit_cast(unsigned, w0v[2 * j2 + 1]) + 0x8000u;
            ((unsigned*)&A0i)[j2] = __builtin_amdgcn_perm(hi0, lo0, 0x07060302u);
            unsigned lo1 = __builtin_bit_cast(unsigned, w1v[2 * j2])     + 0x8000u;
            unsigned hi1 = __builtin_bit_cast(unsigned, w1v[2 * j2 + 1]) + 0x8000u;
            ((unsigned*)&A1i)[j2] = __builtin_amdgcn_perm(hi1, lo1, 0x07060302u);
        }
        short8 A0 = __builtin_bit_cast(short8, A0i);
        short8 A1 = __builtin_bit_cast(short8, A1i);

        #pragma unroll
        for (int nf = 0; nf < 8; ++nf) {
            C0[nf] = __builtin_amdgcn_mfma_f32_16x16x32_bf16(A0, Bf[nf], C0[nf], 0, 0, 0);
            C1[nf] = __builtin_amdgcn_mfma_f32_16x16x32_bf16(A1, Bf[nf], C1[nf], 0, 0, 0);
        }
    }

    den0 += __shfl_xor(den0, 16); den0 += __shfl_xor(den0, 32);
    den1 += __shfl_xor(den1, 16); den1 += __shfl_xor(den1, 32);
    if (q == 0) { DS[wv][L] = den0; DS[wv][16 + L] = den1; }

    // ---- cross-wave C reduction
    if (wv == 0 || wv == 2) {
        float* bp = (wv == 0) ? buf0 : buf1;
        #pragma unroll
        for (int mf = 0; mf < 2; ++mf) {
            const floatx4* Cf = mf ? C1 : C0;
            #pragma unroll
            for (int nf = 0; nf < 8; ++nf)
                #pragma unroll
                for (int r = 0; r < 4; ++r)
                    bp[(mf * 16 + q * 4 + r) * 132 + nf * 16 + L] = Cf[nf][r];
        }
    }
    __syncthreads();
    if (wv == 1 || wv == 3) {
        float* bp = (wv == 1) ? buf0 : buf1;
        #pragma unroll
        for (int mf = 0; mf < 2; ++mf) {
            const floatx4* Cf = mf ? C1 : C0;
            #pragma unroll
            for (int nf = 0; nf < 8; ++nf)
                #pragma unroll
                for (int r = 0; r < 4; ++r)
                    bp[(mf * 16 + q * 4 + r) * 132 + nf * 16 + L] += Cf[nf][r];
        }
    }
    __syncthreads();

    // ---- inline h_res (3-term split MFMA); machine m = m0 + 2L + mf for A-frag mf
    float fA[2][2][8];
    #pragma unroll
    for (int mf = 0; mf < 2; ++mf) {
        const float* fr = feat_mac + ((size_t)b * N_MAC + m0 + 2 * L + mf) * DIM + q * 8;
        #pragma unroll
        for (int ks = 0; ks < 2; ++ks) {
            float4 v0 = *(const float4*)(fr + ks * 32);
            float4 v1 = *(const float4*)(fr + ks * 32 + 4);
            fA[mf][ks][0] = v0.x; fA[mf][ks][1] = v0.y; fA[mf][ks][2] = v0.z; fA[mf][ks][3] = v0.w;
            fA[mf][ks][4] = v1.x; fA[mf][ks][5] = v1.y; fA[mf][ks][6] = v1.z; fA[mf][ks][7] = v1.w;
        }
    }
    short8 Ah[2][2], Al[2][2];
    #pragma unroll
    for (int mf = 0; mf < 2; ++mf)
        #pragma unroll
        for (int ks = 0; ks < 2; ++ks)
            #pragma unroll
            for (int j = 0; j < 8; ++j) {
                float x = fA[mf][ks][j];
                unsigned short h = f2bf(x);
                Ah[mf][ks][j] = (short)h;
                Al[mf][ks][j] = (short)f2bf(x - bf2f(h));
            }
    floatx4 R[2][2];
    R[0][0] = (floatx4)0.f; R[0][1] = (floatx4)0.f;
    R[1][0] = (floatx4)0.f; R[1][1] = (floatx4)0.f;
    #pragma unroll
    for (int ks = 0; ks < 2; ++ks) {
        #pragma unroll
        for (int nfl = 0; nfl < 2; ++nfl) {
            const float* wp = res_w + (size_t)((wv * 2 + nfl) * 16 + L) * DIM + ks * 32 + q * 8;
            float4 u0 = *(const float4*)(wp);
            float4 u1 = *(const float4*)(wp + 4);
            float bw[8] = {u0.x, u0.y, u0.z, u0.w, u1.x, u1.y, u1.z, u1.w};
            short8 Bh, Bl;
            #pragma unroll
            for (int j = 0; j < 8; ++j) {
                unsigned short h = f2bf(bw[j]);
                Bh[j] = (short)h;
                Bl[j] = (short)f2bf(bw[j] - bf2f(h));
            }
            #pragma unroll
            for (int mf = 0; mf < 2; ++mf) {
                R[mf][nfl] = __builtin_amdgcn_mfma_f32_16x16x32_bf16(Ah[mf][ks], Bh, R[mf][nfl], 0, 0, 0);
                R[mf][nfl] = __builtin_amdgcn_mfma_f32_16x16x32_bf16(Al[mf][ks], Bh, R[mf][nfl], 0, 0, 0);
                R[mf][nfl] = __builtin_amdgcn_mfma_f32_16x16x32_bf16(Ah[mf][ks], Bl, R[mf][nfl], 0, 0, 0);
            }
        }
    }

    // ---- epilogue: machine m = m0 + 2*fragrow + mf; wave covers its 2 n-frags
    #pragma unroll
    for (int mf = 0; mf < 2; ++mf) {
        #pragma unroll
        for (int r = 0; r < 4; ++r) {
            int fragrow = q * 4 + r;
            int m = m0 + 2 * fragrow + mf;
            float inv = 1.0f / (DS[0][mf * 16 + fragrow] + DS[1][mf * 16 + fragrow]
                              + DS[2][mf * 16 + fragrow] + DS[3][mf * 16 + fragrow]);
            size_t obase = ((size_t)b * N_MAC + m) * KOUT;
            #pragma unroll
            for (int nfl = 0; nfl < 2; ++nfl) {
                int col = (wv * 2 + nfl) * 16 + L;
                float num = buf0[(mf * 16 + fragrow) * 132 + col]
                          + buf1[(mf * 16 + fragrow) * 132 + col];
                out[obase + col] = num * inv + R[mf][nfl][r];
            }
        }
    }
}

extern "C" void kernel_launch(void* const* d_in, const int* in_sizes, int n_in,
                              void* d_out, int out_size, void* d_ws, size_t ws_size,
                              hipStream_t stream) {
    const int*   adj       = (const int*)d_in[0];
    const int*   bidx      = (const int*)d_in[1];
    const float* feat_ope  = (const float*)d_in[2];
    const float* feat_mac  = (const float*)d_in[3];
    const float* ope_w     = (const float*)d_in[4];
    const float* mac_w     = (const float*)d_in[5];
    const float* ope_alpha = (const float*)d_in[6];
    const float* mac_alpha = (const float*)d_in[7];
    const float* res_w     = (const float*)d_in[8];
    float* out = (float*)d_out;

    char* ws = (char*)d_ws;
    unsigned short* h_f = (unsigned short*)ws;                        // 16 MiB fragment-major bf16
    float2* pq          = (float2*)(ws + (size_t)(16 << 20));         // 512 KiB
    unsigned long long* pk = (unsigned long long*)(ws + (size_t)(17 << 20)); // 8 MiB packed masks

    k_prep<<<1024, 256, 0, stream>>>(feat_ope, ope_w, ope_alpha, h_f, pq, adj, bidx, pk);
    k_attn<<<dim3(N_MAC / 32, NB), 256, 0, stream>>>(pk, h_f, pq, feat_mac,
                                                     mac_w, mac_alpha, res_w, out);
}

// Round 3
// 691.888 us; speedup vs baseline: 1.0246x; 1.0246x over previous
//
#include <hip/hip_runtime.h>

#define N_OPE 2048
#define N_MAC 1024
#define DIM   64
#define KOUT  128
#define NB    32

typedef __attribute__((ext_vector_type(8))) short short8;
typedef __attribute__((ext_vector_type(4))) float floatx4;

static __device__ __forceinline__ unsigned short f2bf(float f) {
    unsigned int u = __builtin_bit_cast(unsigned int, f);
    u += 0x7fffu + ((u >> 16) & 1u);   // round-to-nearest-even
    return (unsigned short)(u >> 16);
}
static __device__ __forceinline__ float bf2f(unsigned short h) {
    unsigned int u = ((unsigned int)h) << 16;
    return __builtin_bit_cast(float, u);
}

// ---------------- kernel 1: h_ope via 3-term bf16 MFMA -> h_f (FRAGMENT-MAJOR bf16),
//                  plus pq[o] = (exp(attn_ope), exp(0.2*attn_ope)) from exact C.alpha ----
// h_f[b][oc][nf][lane] holds the exact short8 k_attn's lane wants: both k_ope stores
// and k_attn loads are single-segment 1KiB/instr dwordx4.
__global__ __launch_bounds__(256, 2) void k_ope(const float* __restrict__ feat,
        const float* __restrict__ w, const float* __restrict__ alpha,
        unsigned short* __restrict__ h_f, float2* __restrict__ pq)
{
    int wid = threadIdx.x >> 6, lane = threadIdx.x & 63;
    int L = lane & 15, q = lane >> 4;
    int base = blockIdx.x * 128 + wid * 32;           // row base for this wave
    int b = base >> 11;                                // rows per batch = 2048
    int o0w = base & (N_OPE - 1);

    float fA[2][2][8];                                 // [mf][ks][j]
    #pragma unroll
    for (int mf = 0; mf < 2; ++mf) {
        const float* fr = feat + (size_t)(base + mf * 16 + L) * DIM + q * 8;
        #pragma unroll
        for (int ks = 0; ks < 2; ++ks) {
            float4 v0 = *(const float4*)(fr + ks * 32);
            float4 v1 = *(const float4*)(fr + ks * 32 + 4);
            fA[mf][ks][0] = v0.x; fA[mf][ks][1] = v0.y; fA[mf][ks][2] = v0.z; fA[mf][ks][3] = v0.w;
            fA[mf][ks][4] = v1.x; fA[mf][ks][5] = v1.y; fA[mf][ks][6] = v1.z; fA[mf][ks][7] = v1.w;
        }
    }

    short8 Ah[2][2], Al[2][2];
    #pragma unroll
    for (int mf = 0; mf < 2; ++mf)
        #pragma unroll
        for (int ks = 0; ks < 2; ++ks)
            #pragma unroll
            for (int j = 0; j < 8; ++j) {
                float x = fA[mf][ks][j];
                unsigned short h = f2bf(x);
                Ah[mf][ks][j] = (short)h;
                Al[mf][ks][j] = (short)f2bf(x - bf2f(h));
            }

    floatx4 C[2][8];
    #pragma unroll
    for (int mf = 0; mf < 2; ++mf)
        #pragma unroll
        for (int nf = 0; nf < 8; ++nf) C[mf][nf] = (floatx4)0.f;

    #pragma unroll
    for (int ks = 0; ks < 2; ++ks) {
        #pragma unroll
        for (int nf = 0; nf < 8; ++nf) {
            const float* wp = w + (size_t)(nf * 16 + L) * DIM + ks * 32 + q * 8;
            float4 u0 = *(const float4*)(wp);
            float4 u1 = *(const float4*)(wp + 4);
            float bw[8] = {u0.x, u0.y, u0.z, u0.w, u1.x, u1.y, u1.z, u1.w};
            short8 Bh, Bl;
            #pragma unroll
            for (int j = 0; j < 8; ++j) {
                unsigned short h = f2bf(bw[j]);
                Bh[j] = (short)h;
                Bl[j] = (short)f2bf(bw[j] - bf2f(h));
            }
            #pragma unroll
            for (int mf = 0; mf < 2; ++mf) {
                C[mf][nf] = __builtin_amdgcn_mfma_f32_16x16x32_bf16(Ah[mf][ks], Bh, C[mf][nf], 0, 0, 0);
                C[mf][nf] = __builtin_amdgcn_mfma_f32_16x16x32_bf16(Al[mf][ks], Bh, C[mf][nf], 0, 0, 0);
                C[mf][nf] = __builtin_amdgcn_mfma_f32_16x16x32_bf16(Ah[mf][ks], Bl, C[mf][nf], 0, 0, 0);
            }
        }
    }

    // ---- pq from exact fp32 C . alpha (row = mf*16+q*4+r, col = nf*16+L)
    float alf[8];
    #pragma unroll
    for (int nf = 0; nf < 8; ++nf) alf[nf] = alpha[nf * 16 + L];
    #pragma unroll
    for (int mf = 0; mf < 2; ++mf) {
        #pragma unroll
        for (int r = 0; r < 4; ++r) {
            float s = 0.f;
            #pragma unroll
            for (int nf = 0; nf < 8; ++nf) s = fmaf(C[mf][nf][r], alf[nf], s);
            s += __shfl_xor(s, 1); s += __shfl_xor(s, 2);
            s += __shfl_xor(s, 4); s += __shfl_xor(s, 8);
            if (L == 0)
                pq[base + mf * 16 + q * 4 + r] = make_float2(__expf(s), __expf(0.2f * s));
        }
    }

    // ---- transpose via per-wave LDS slice (stride 40 shorts => 16B-aligned b128 reads)
    __shared__ unsigned short T[4][128 * 40];
    #pragma unroll
    for (int mf = 0; mf < 2; ++mf)
        #pragma unroll
        for (int nf = 0; nf < 8; ++nf)
            #pragma unroll
            for (int r = 0; r < 4; ++r)
                T[wid][(nf * 16 + L) * 40 + mf * 16 + q * 4 + r] = f2bf(C[mf][nf][r]);
    __syncthreads();

    // ---- fragment-major store: lane (L,q) emits exactly k_attn lane's short8
    int oc = o0w >> 5;
    unsigned short* dst = h_f + ((((size_t)b * 64 + oc) * 8) * 64 + lane) * 8;
    #pragma unroll
    for (int nf = 0; nf < 8; ++nf) {
        short8 v = *(const short8*)&T[wid][(nf * 16 + L) * 40 + q * 8];
        *(short8*)(dst + (size_t)nf * 512) = v;
    }
}

// ---------------- kernel 2: fully fused mask->softmax->MFMA + h_res ----------------
// 4 waves, 4-way K-split, even/odd m-pairing (int2 masks), fragment-major B loads.
__global__ __launch_bounds__(256) void k_attn(const int* __restrict__ adj,
        const int* __restrict__ bidx,
        const unsigned short* __restrict__ h_f,
        const float2* __restrict__ pq,
        const float* __restrict__ feat_mac,
        const float* __restrict__ mac_w, const float* __restrict__ mac_alpha,
        const float* __restrict__ res_w,
        float* __restrict__ out)
{
    int b  = blockIdx.y;
    int m0 = blockIdx.x * 32;
    int t = threadIdx.x, wv = t >> 6, lane = t & 63;
    int L = lane & 15, q = lane >> 4;

    __shared__ float buf0[32 * 132];
    __shared__ float buf1[32 * 132];
    __shared__ float waS[64];
    __shared__ float amS[32];
    __shared__ float DS[4][32];

    // ---- wa[d] = sum_n mac_w[n][d]*mac_alpha[n]
    {
        int d = t & 63, seg = t >> 6;
        float p = 0.f;
        #pragma unroll 8
        for (int n = seg * 32; n < seg * 32 + 32; ++n)
            p = fmaf(mac_w[n * DIM + d], mac_alpha[n], p);
        buf0[seg * 64 + d] = p;
    }
    __syncthreads();
    if (t < 64) waS[t] = buf0[t] + buf0[64 + t] + buf0[128 + t] + buf0[192 + t];
    __syncthreads();
    // ---- am[m] = feat_mac[b][m0+m] . waS
    {
        int row = t & 31, seg = t >> 5;
        const float* fr = feat_mac + ((size_t)b * N_MAC + m0 + row) * DIM + seg * 8;
        float p = 0.f;
        #pragma unroll
        for (int k = 0; k < 8; ++k) p = fmaf(fr[k], waS[seg * 8 + k], p);
        buf1[seg * 32 + row] = p;
    }
    __syncthreads();
    if (t < 32) {
        float s = 0.f;
        #pragma unroll
        for (int sg = 0; sg < 8; ++sg) s += buf1[sg * 32 + t];
        amS[t] = s;
    }
    __syncthreads();

    float2 amv = *(const float2*)&amS[2 * L];          // frag0: m0+2L, frag1: m0+2L+1
    float pM0 = __expf(amv.x), qM0 = __expf(0.2f * amv.x);
    float pM1 = __expf(amv.y), qM1 = __expf(0.2f * amv.y);

    const int* adjt = adj + (size_t)bidx[b] * (N_OPE * N_MAC);
    const unsigned short* hfb = h_f + (size_t)b * (64 * 8 * 64 * 8);
    const float2* pqb = pq + (size_t)b * N_OPE;

    floatx4 C0[8], C1[8];
    #pragma unroll
    for (int i = 0; i < 8; ++i) { C0[i] = (floatx4)0.f; C1[i] = (floatx4)0.f; }
    float den0 = 0.f, den1 = 0.f;

    int oBeg = wv * (N_OPE / 4);
    for (int o0 = oBeg; o0 < oBeg + N_OPE / 4; o0 += 32) {
        int ob = o0 + q * 8;
        float4 pv0 = *(const float4*)(pqb + ob);
        float4 pv1 = *(const float4*)(pqb + ob + 2);
        float4 pv2 = *(const float4*)(pqb + ob + 4);
        float4 pv3 = *(const float4*)(pqb + ob + 6);
        float pA[8] = {pv0.x, pv0.z, pv1.x, pv1.z, pv2.x, pv2.z, pv3.x, pv3.z};
        float qA[8] = {pv0.y, pv0.w, pv1.y, pv1.w, pv2.y, pv2.w, pv3.y, pv3.w};

        int2 mk[8];
        #pragma unroll
        for (int j = 0; j < 8; ++j)
            mk[j] = *(const int2*)(adjt + (size_t)(ob + j) * N_MAC + m0 + 2 * L);

        const unsigned short* fp = hfb + (((size_t)(o0 >> 5) * 8) * 64 + lane) * 8;
        short8 Bf[8];
        #pragma unroll
        for (int nf = 0; nf < 8; ++nf)
            Bf[nf] = *(const short8*)(fp + (size_t)nf * 512);

        float w0v[8], w1v[8];
        #pragma unroll
        for (int j = 0; j < 8; ++j) {
            float tp0 = pA[j] * pM0;
            float w0 = (tp0 >= 1.0f) ? tp0 : qA[j] * qM0;
            w0 = (mk[j].x == 1) ? w0 : 0.f;
            den0 += w0; w0v[j] = w0;
            float tp1 = pA[j] * pM1;
            float w1 = (tp1 >= 1.0f) ? tp1 : qA[j] * qM1;
            w1 = (mk[j].y == 1) ? w1 : 0.f;
            den1 += w1; w1v[j] = w1;
        }
        int4 A0i, A1i;
        #pragma unroll
        for (int j2 = 0; j2 < 4; ++j2) {
            unsigned lo0 = __builtin_bit_cast(unsigned, w0v[2 * j2])     + 0x8000u;
            unsigned hi0 = __builtin_bit_cast(unsigned, w0v[2 * j2 + 1]) + 0x8000u;
            ((unsigned*)&A0i)[j2] = __builtin_amdgcn_perm(hi0, lo0, 0x07060302u);
            unsigned lo1 = __builtin_bit_cast(unsigned, w1v[2 * j2])     + 0x8000u;
            unsigned hi1 = __builtin_bit_cast(unsigned, w1v[2 * j2 + 1]) + 0x8000u;
            ((unsigned*)&A1i)[j2] = __builtin_amdgcn_perm(hi1, lo1, 0x07060302u);
        }
        short8 A0 = __builtin_bit_cast(short8, A0i);
        short8 A1 = __builtin_bit_cast(short8, A1i);

        #pragma unroll
        for (int nf = 0; nf < 8; ++nf) {
            C0[nf] = __builtin_amdgcn_mfma_f32_16x16x32_bf16(A0, Bf[nf], C0[nf], 0, 0, 0);
            C1[nf] = __builtin_amdgcn_mfma_f32_16x16x32_bf16(A1, Bf[nf], C1[nf], 0, 0, 0);
        }
    }

    den0 += __shfl_xor(den0, 16); den0 += __shfl_xor(den0, 32);
    den1 += __shfl_xor(den1, 16); den1 += __shfl_xor(den1, 32);
    if (q == 0) { DS[wv][L] = den0; DS[wv][16 + L] = den1; }

    // ---- cross-wave C reduction
    if (wv == 0 || wv == 2) {
        float* bp = (wv == 0) ? buf0 : buf1;
        #pragma unroll
        for (int mf = 0; mf < 2; ++mf) {
            const floatx4* Cf = mf ? C1 : C0;
            #pragma unroll
            for (int nf = 0; nf < 8; ++nf)
                #pragma unroll
                for (int r = 0; r < 4; ++r)
                    bp[(mf * 16 + q * 4 + r) * 132 + nf * 16 + L] = Cf[nf][r];
        }
    }
    __syncthreads();
    if (wv == 1 || wv == 3) {
        float* bp = (wv == 1) ? buf0 : buf1;
        #pragma unroll
        for (int mf = 0; mf < 2; ++mf) {
            const floatx4* Cf = mf ? C1 : C0;
            #pragma unroll
            for (int nf = 0; nf < 8; ++nf)
                #pragma unroll
                for (int r = 0; r < 4; ++r)
                    bp[(mf * 16 + q * 4 + r) * 132 + nf * 16 + L] += Cf[nf][r];
        }
    }
    __syncthreads();

    // ---- inline h_res (3-term split MFMA); machine m = m0 + 2L + mf for A-frag mf
    float fA[2][2][8];
    #pragma unroll
    for (int mf = 0; mf < 2; ++mf) {
        const float* fr = feat_mac + ((size_t)b * N_MAC + m0 + 2 * L + mf) * DIM + q * 8;
        #pragma unroll
        for (int ks = 0; ks < 2; ++ks) {
            float4 v0 = *(const float4*)(fr + ks * 32);
            float4 v1 = *(const float4*)(fr + ks * 32 + 4);
            fA[mf][ks][0] = v0.x; fA[mf][ks][1] = v0.y; fA[mf][ks][2] = v0.z; fA[mf][ks][3] = v0.w;
            fA[mf][ks][4] = v1.x; fA[mf][ks][5] = v1.y; fA[mf][ks][6] = v1.z; fA[mf][ks][7] = v1.w;
        }
    }
    short8 Ah[2][2], Al[2][2];
    #pragma unroll
    for (int mf = 0; mf < 2; ++mf)
        #pragma unroll
        for (int ks = 0; ks < 2; ++ks)
            #pragma unroll
            for (int j = 0; j < 8; ++j) {
                float x = fA[mf][ks][j];
                unsigned short h = f2bf(x);
                Ah[mf][ks][j] = (short)h;
                Al[mf][ks][j] = (short)f2bf(x - bf2f(h));
            }
    floatx4 R[2][2];
    R[0][0] = (floatx4)0.f; R[0][1] = (floatx4)0.f;
    R[1][0] = (floatx4)0.f; R[1][1] = (floatx4)0.f;
    #pragma unroll
    for (int ks = 0; ks < 2; ++ks) {
        #pragma unroll
        for (int nfl = 0; nfl < 2; ++nfl) {
            const float* wp = res_w + (size_t)((wv * 2 + nfl) * 16 + L) * DIM + ks * 32 + q * 8;
            float4 u0 = *(const float4*)(wp);
            float4 u1 = *(const float4*)(wp + 4);
            float bw[8] = {u0.x, u0.y, u0.z, u0.w, u1.x, u1.y, u1.z, u1.w};
            short8 Bh, Bl;
            #pragma unroll
            for (int j = 0; j < 8; ++j) {
                unsigned short h = f2bf(bw[j]);
                Bh[j] = (short)h;
                Bl[j] = (short)f2bf(bw[j] - bf2f(h));
            }
            #pragma unroll
            for (int mf = 0; mf < 2; ++mf) {
                R[mf][nfl] = __builtin_amdgcn_mfma_f32_16x16x32_bf16(Ah[mf][ks], Bh, R[mf][nfl], 0, 0, 0);
                R[mf][nfl] = __builtin_amdgcn_mfma_f32_16x16x32_bf16(Al[mf][ks], Bh, R[mf][nfl], 0, 0, 0);
                R[mf][nfl] = __builtin_amdgcn_mfma_f32_16x16x32_bf16(Ah[mf][ks], Bl, R[mf][nfl], 0, 0, 0);
            }
        }
    }

    // ---- epilogue: machine m = m0 + 2*fragrow + mf; wave covers its 2 n-frags
    #pragma unroll
    for (int mf = 0; mf < 2; ++mf) {
        #pragma unroll
        for (int r = 0; r < 4; ++r) {
            int fragrow = q * 4 + r;
            int m = m0 + 2 * fragrow + mf;
            float inv = 1.0f / (DS[0][mf * 16 + fragrow] + DS[1][mf * 16 + fragrow]
                              + DS[2][mf * 16 + fragrow] + DS[3][mf * 16 + fragrow]);
            size_t obase = ((size_t)b * N_MAC + m) * KOUT;
            #pragma unroll
            for (int nfl = 0; nfl < 2; ++nfl) {
                int col = (wv * 2 + nfl) * 16 + L;
                float num = buf0[(mf * 16 + fragrow) * 132 + col]
                          + buf1[(mf * 16 + fragrow) * 132 + col];
                out[obase + col] = num * inv + R[mf][nfl][r];
            }
        }
    }
}

extern "C" void kernel_launch(void* const* d_in, const int* in_sizes, int n_in,
                              void* d_out, int out_size, void* d_ws, size_t ws_size,
                              hipStream_t stream) {
    const int*   adj       = (const int*)d_in[0];
    const int*   bidx      = (const int*)d_in[1];
    const float* feat_ope  = (const float*)d_in[2];
    const float* feat_mac  = (const float*)d_in[3];
    const float* ope_w     = (const float*)d_in[4];
    const float* mac_w     = (const float*)d_in[5];
    const float* ope_alpha = (const float*)d_in[6];
    const float* mac_alpha = (const float*)d_in[7];
    const float* res_w     = (const float*)d_in[8];
    float* out = (float*)d_out;

    char* ws = (char*)d_ws;
    unsigned short* h_f = (unsigned short*)ws;                // 16 MiB fragment-major bf16
    float2* pq          = (float2*)(ws + (size_t)(16 << 20)); // 512 KiB

    k_ope<<<512, 256, 0, stream>>>(feat_ope, ope_w, ope_alpha, h_f, pq);
    k_attn<<<dim3(N_MAC / 32, NB), 256, 0, stream>>>(adj, bidx, h_f, pq, feat_mac,
                                                     mac_w, mac_alpha, res_w, out);
}